// Round 10
// baseline (532.864 us; speedup 1.0000x reference)
//
#include <hip/hip_runtime.h>
#include <hip/hip_fp16.h>

#define IN_DIM 64
#define HID 32
#define SHIFT 8
#define BKEYS 256            // nodes per bin
#define CAP 4608             // bin capacity (mean 4096, sigma ~64 -> +8 sigma)
#define HCAP 2560            // half-bin CSR capacity (mean 2048, sigma ~45)
#define CHUNK 2048           // edges per multisplit task (1 int4 per thread)
#define MAXB 512             // max bins (N <= 131072)

// ---- K0: zero reservation counters + grid barrier ----
__global__ void zero_kernel(unsigned* __restrict__ p) {
    int i = threadIdx.x + blockIdx.x * 256;
    if (i < 2 * MAXB + 1) p[i] = 0u;     // gcur_d[512] | gcur_s[512] | bar[1]
}

// device-scope grid barrier, cumulative target (counter never resets)
__device__ __forceinline__ void grid_barrier(unsigned* bar, unsigned target) {
    __syncthreads();
    __threadfence();                      // release: flush this block's writes
    if (threadIdx.x == 0) {
        atomicAdd(bar, 1u);
        while (atomicAdd(bar, 0u) < target) __builtin_amdgcn_s_sleep(2);
    }
    __syncthreads();
    __threadfence();                      // acquire: discard stale lines
}

// ---- fused persistent kernel: multisplit -> degxw -> csrgather ----
__global__ __launch_bounds__(512, 8) void fused_kernel(
    const int* __restrict__ src, const int* __restrict__ dst,
    const float* __restrict__ X, const float* __restrict__ W,
    const float* __restrict__ bias, float* __restrict__ out,
    unsigned* __restrict__ gcur_d, unsigned* __restrict__ gcur_s,
    unsigned* __restrict__ bar,
    unsigned* __restrict__ bkt_pairs, unsigned char* __restrict__ bkt_srcs,
    unsigned short* __restrict__ h16,
    int E, int N, int NB, int nchunks)
{
    __shared__ unsigned smem[3072];       // 12 KB, unioned across phases
    int t = threadIdx.x;
    int nblocks = gridDim.x;

    // ================= phase 1: multisplit =================
    {
        unsigned* hist_d = smem;
        unsigned* hist_s = smem + 512;
        unsigned* cur_d  = smem + 1024;
        unsigned* cur_s  = smem + 1536;
        unsigned* gb_d   = smem + 2048;
        unsigned* gb_s   = smem + 2560;
        for (int task = blockIdx.x; task < nchunks; task += nblocks) {
            __syncthreads();
            hist_d[t] = 0; hist_s[t] = 0; cur_d[t] = 0; cur_s[t] = 0;
            __syncthreads();
            int e0 = task * CHUNK;
            int cnt = min(CHUNK, E - e0);
            int n4 = cnt >> 2;
            int4 sa = make_int4(-1, -1, -1, -1), da = sa;
            if (t < n4) { sa = ((const int4*)(src + e0))[t]; da = ((const int4*)(dst + e0))[t]; }
            int sc = -1, dc = -1;
            int ti = (n4 << 2) + t;
            if (t < (cnt & 3)) { sc = src[e0 + ti]; dc = dst[e0 + ti]; }
            if (da.x >= 0) {
                atomicAdd(&hist_d[da.x >> SHIFT], 1u); atomicAdd(&hist_s[sa.x >> SHIFT], 1u);
                atomicAdd(&hist_d[da.y >> SHIFT], 1u); atomicAdd(&hist_s[sa.y >> SHIFT], 1u);
                atomicAdd(&hist_d[da.z >> SHIFT], 1u); atomicAdd(&hist_s[sa.z >> SHIFT], 1u);
                atomicAdd(&hist_d[da.w >> SHIFT], 1u); atomicAdd(&hist_s[sa.w >> SHIFT], 1u);
            }
            if (dc >= 0) { atomicAdd(&hist_d[dc >> SHIFT], 1u); atomicAdd(&hist_s[sc >> SHIFT], 1u); }
            __syncthreads();
            if (t < NB) {
                unsigned hd = hist_d[t], hs = hist_s[t];
                if (hd) gb_d[t] = atomicAdd(&gcur_d[t], hd);
                if (hs) gb_s[t] = atomicAdd(&gcur_s[t], hs);
            }
            __syncthreads();
            int dv[5] = {da.x, da.y, da.z, da.w, dc};
            int sv[5] = {sa.x, sa.y, sa.z, sa.w, sc};
#pragma unroll
            for (int j = 0; j < 5; ++j) {
                if (dv[j] < 0) continue;
                int kd = dv[j] >> SHIFT;
                unsigned pos = gb_d[kd] + atomicAdd(&cur_d[kd], 1u);
                if (pos < CAP)
                    bkt_pairs[(size_t)kd * CAP + pos] =
                        (((unsigned)dv[j] & (BKEYS - 1)) << 17) | (unsigned)sv[j];
                int ks = sv[j] >> SHIFT;
                unsigned pos2 = gb_s[ks] + atomicAdd(&cur_s[ks], 1u);
                if (pos2 < CAP)
                    bkt_srcs[(size_t)ks * CAP + pos2] = (unsigned char)(sv[j] & (BKEYS - 1));
            }
        }
    }
    grid_barrier(bar, (unsigned)nblocks);

    // ================= phase 2: degxw (half-bins) =================
    {
        float* Ws = (float*)smem;                 // 8 KB
        unsigned* cnt = smem + 2048;              // 128
        float* nrm = (float*)(smem + 2176);       // 128
        ((float4*)Ws)[t] = ((const float4*)W)[t]; // stage W once per block
        int q = t & 7, ln = t >> 3;               // 8 threads/node
        for (int task = blockIdx.x; task < 2 * NB; task += nblocks) {
            __syncthreads();
            if (t < 128) cnt[t] = 0;
            __syncthreads();
            int bin = task >> 1;
            unsigned half = task & 1;
            unsigned m = gcur_s[bin]; if (m > CAP) m = CAP;
            const unsigned char* bs = bkt_srcs + (size_t)bin * CAP;
            const uchar4* bs4 = (const uchar4*)bs;
            unsigned m4 = m >> 2;
            for (unsigned i = t; i < m4; i += 512) {
                uchar4 kk = bs4[i];
                if ((kk.x >> 7) == half) atomicAdd(&cnt[kk.x & 127], 1u);
                if ((kk.y >> 7) == half) atomicAdd(&cnt[kk.y & 127], 1u);
                if ((kk.z >> 7) == half) atomicAdd(&cnt[kk.z & 127], 1u);
                if ((kk.w >> 7) == half) atomicAdd(&cnt[kk.w & 127], 1u);
            }
            for (unsigned i = (m4 << 2) + t; i < m; i += 512) {
                unsigned k = bs[i];
                if ((k >> 7) == half) atomicAdd(&cnt[k & 127], 1u);
            }
            __syncthreads();
            if (t < 128) nrm[t] = rsqrtf(fmaxf((float)cnt[t], 1.0f));
            __syncthreads();
#pragma unroll
            for (int pass = 0; pass < 2; ++pass) {
                int lv = pass * 64 + ln;
                int v = bin * BKEYS + (int)half * 128 + lv;
                if (v < N) {
                    const float4* Xr = (const float4*)(X + (size_t)v * IN_DIM);
                    float4 acc = make_float4(0.f, 0.f, 0.f, 0.f);
#pragma unroll
                    for (int kk = 0; kk < 16; ++kk) {
                        float4 xv = Xr[kk];
                        int k0 = kk * 4;
                        float4 w0 = ((float4*)Ws)[(k0 + 0) * 8 + q];
                        float4 w1 = ((float4*)Ws)[(k0 + 1) * 8 + q];
                        float4 w2 = ((float4*)Ws)[(k0 + 2) * 8 + q];
                        float4 w3 = ((float4*)Ws)[(k0 + 3) * 8 + q];
                        acc.x += xv.x * w0.x + xv.y * w1.x + xv.z * w2.x + xv.w * w3.x;
                        acc.y += xv.x * w0.y + xv.y * w1.y + xv.z * w2.y + xv.w * w3.y;
                        acc.z += xv.x * w0.z + xv.y * w1.z + xv.z * w2.z + xv.w * w3.z;
                        acc.w += xv.x * w0.w + xv.y * w1.w + xv.z * w2.w + xv.w * w3.w;
                    }
                    float s = nrm[lv];
                    __half2 a  = __floats2half2_rn(acc.x * s, acc.y * s);
                    __half2 b2 = __floats2half2_rn(acc.z * s, acc.w * s);
                    uint2 u;
                    u.x = *(unsigned*)&a;
                    u.y = *(unsigned*)&b2;
                    ((uint2*)h16)[(size_t)v * 8 + q] = u;
                }
            }
        }
    }
    grid_barrier(bar, 2u * (unsigned)nblocks);

    // ================= phase 3: csrgather (half-bins) =================
    {
        unsigned* cnt = smem;           // 128
        unsigned* ex  = smem + 128;     // 128
        unsigned* cur = smem + 256;     // 128
        unsigned* ecsr = smem + 384;    // HCAP = 2560 -> ends at word 2944
        int lane = t & 63, w = t >> 6;
        int hsel = lane >> 5, slot = (lane >> 2) & 7, q = lane & 3;
        float4 bq0 = ((const float4*)bias)[q * 2];
        float4 bq1 = ((const float4*)bias)[q * 2 + 1];
        for (int task = blockIdx.x; task < 2 * NB; task += nblocks) {
            __syncthreads();
            if (t < 128) { cnt[t] = 0; cur[t] = 0; }
            __syncthreads();
            int bin = task >> 1;
            unsigned half = task & 1;
            unsigned m = gcur_d[bin]; if (m > CAP) m = CAP;
            const unsigned* bp = bkt_pairs + (size_t)bin * CAP;
            for (unsigned i = t; i < m; i += 512) {
                unsigned k = bp[i] >> 17;
                if ((k >> 7) == half) atomicAdd(&cnt[k & 127], 1u);
            }
            __syncthreads();
            if (t < 128) ex[t] = cnt[t];
            __syncthreads();
            for (int off = 1; off < 128; off <<= 1) {
                unsigned u = (t >= off && t < 128) ? ex[t - off] : 0;
                __syncthreads();
                if (t < 128) ex[t] += u;     // inclusive
                __syncthreads();
            }
            for (unsigned i = t; i < m; i += 512) {
                unsigned p = bp[i];
                unsigned k = p >> 17;
                if ((k >> 7) == half) {
                    unsigned kk = k & 127;
                    unsigned pos = (ex[kk] - cnt[kk]) + atomicAdd(&cur[kk], 1u);
                    if (pos < HCAP) ecsr[pos] = p & 0x1FFFFu;
                }
            }
            __syncthreads();
            for (int j = 0; j < 8; ++j) {
                int lv = w * 16 + j * 2 + hsel;   // 0..127
                unsigned dg = cnt[lv];
                unsigned st = ex[lv] - dg;
                unsigned en = st + dg; if (en > HCAP) en = HCAP;
                float a0=0.f,a1=0.f,a2=0.f,a3=0.f,a4=0.f,a5=0.f,a6=0.f,a7=0.f;
                unsigned u = st + slot;
                for (; u + 8 < en; u += 16) {     // 2 independent 16B loads in flight
                    unsigned s0 = ecsr[u];
                    unsigned s1 = ecsr[u + 8];
                    uint4 hv0 = ((const uint4*)h16)[(size_t)s0 * 4 + q];
                    uint4 hv1 = ((const uint4*)h16)[(size_t)s1 * 4 + q];
                    __half2* hp0 = (__half2*)&hv0;
                    __half2* hp1 = (__half2*)&hv1;
                    float2 f0 = __half22float2(hp0[0]), g0 = __half22float2(hp1[0]);
                    float2 f1 = __half22float2(hp0[1]), g1 = __half22float2(hp1[1]);
                    float2 f2 = __half22float2(hp0[2]), g2 = __half22float2(hp1[2]);
                    float2 f3 = __half22float2(hp0[3]), g3 = __half22float2(hp1[3]);
                    a0 += f0.x + g0.x; a1 += f0.y + g0.y;
                    a2 += f1.x + g1.x; a3 += f1.y + g1.y;
                    a4 += f2.x + g2.x; a5 += f2.y + g2.y;
                    a6 += f3.x + g3.x; a7 += f3.y + g3.y;
                }
                if (u < en) {
                    unsigned s = ecsr[u];
                    uint4 hv = ((const uint4*)h16)[(size_t)s * 4 + q];
                    __half2* hp = (__half2*)&hv;
                    float2 f0 = __half22float2(hp[0]);
                    float2 f1 = __half22float2(hp[1]);
                    float2 f2 = __half22float2(hp[2]);
                    float2 f3 = __half22float2(hp[3]);
                    a0 += f0.x; a1 += f0.y; a2 += f1.x; a3 += f1.y;
                    a4 += f2.x; a5 += f2.y; a6 += f3.x; a7 += f3.y;
                }
#pragma unroll
                for (int off = 4; off <= 16; off <<= 1) {
                    a0 += __shfl_xor(a0, off, 64); a1 += __shfl_xor(a1, off, 64);
                    a2 += __shfl_xor(a2, off, 64); a3 += __shfl_xor(a3, off, 64);
                    a4 += __shfl_xor(a4, off, 64); a5 += __shfl_xor(a5, off, 64);
                    a6 += __shfl_xor(a6, off, 64); a7 += __shfl_xor(a7, off, 64);
                }
                int v = bin * BKEYS + (int)half * 128 + lv;
                if (slot == 0 && v < N) {
                    float nv = rsqrtf(fmaxf((float)dg, 1.0f));
                    float4 o0, o1;
                    o0.x = fmaxf(a0 * nv + bq0.x, 0.f);
                    o0.y = fmaxf(a1 * nv + bq0.y, 0.f);
                    o0.z = fmaxf(a2 * nv + bq0.z, 0.f);
                    o0.w = fmaxf(a3 * nv + bq0.w, 0.f);
                    o1.x = fmaxf(a4 * nv + bq1.x, 0.f);
                    o1.y = fmaxf(a5 * nv + bq1.y, 0.f);
                    o1.z = fmaxf(a6 * nv + bq1.z, 0.f);
                    o1.w = fmaxf(a7 * nv + bq1.w, 0.f);
                    float* op = out + (size_t)v * HID + q * 8;
                    *(float4*)op = o0;
                    *(float4*)(op + 4) = o1;
                }
            }
        }
    }
}

extern "C" void kernel_launch(void* const* d_in, const int* in_sizes, int n_in,
                              void* d_out, int out_size, void* d_ws, size_t ws_size,
                              hipStream_t stream) {
    const float* X   = (const float*)d_in[0];
    const int*   src = (const int*)d_in[1];
    const int*   dst = (const int*)d_in[2];
    const float* W   = (const float*)d_in[3];
    const float* b   = (const float*)d_in[4];
    float* out = (float*)d_out;

    int N = in_sizes[0] / IN_DIM;        // 100000
    int E = in_sizes[1];                 // 1600000
    int NB = (N + BKEYS - 1) / BKEYS;    // 391
    int nchunks = (E + CHUNK - 1) / CHUNK;

    // ws: [gcur_d 512 u32][gcur_s 512 u32][bar 1 u32 (+pad 63)]
    //     [bkt_pairs NB*CAP u32][bkt_srcs NB*CAP u8][h16 N*32 halves]
    unsigned* gcur_d = (unsigned*)d_ws;
    unsigned* gcur_s = gcur_d + MAXB;
    unsigned* bar    = gcur_s + MAXB;
    unsigned* bkt_pairs = bar + 64;
    unsigned char* bkt_srcs = (unsigned char*)(bkt_pairs + (size_t)NB * CAP);
    unsigned short* h16 = (unsigned short*)(bkt_srcs + (size_t)NB * CAP);

    // residency-safe persistent grid: blocks/CU from the occupancy API
    int maxb = 0;
    hipError_t e = hipOccupancyMaxActiveBlocksPerMultiprocessor(
        &maxb, (const void*)fused_kernel, 512, 0);
    if (e != hipSuccess || maxb < 1) maxb = 2;   // conservative fallback
    if (maxb > 4) maxb = 4;
    int grid = maxb * 256;
    if (grid > 2 * NB) grid = 2 * NB;            // no more blocks than tasks

    zero_kernel<<<5, 256, 0, stream>>>(gcur_d);
    fused_kernel<<<grid, 512, 0, stream>>>(
        src, dst, X, W, b, out, gcur_d, gcur_s, bar,
        bkt_pairs, bkt_srcs, h16, E, N, NB, nchunks);
}

// Round 11
// 159.629 us; speedup vs baseline: 3.3381x; 3.3381x over previous
//
#include <hip/hip_runtime.h>
#include <hip/hip_fp16.h>

#define IN_DIM 64
#define HID 32
#define SHIFT 8
#define BKEYS 256            // nodes per bin
#define CAP 4608             // bin capacity (mean 4096, sigma ~64 -> +8 sigma)
#define HCAP 2560            // half-bin CSR capacity (mean 2048, sigma ~45)
#define CHUNK 2048           // edges per multisplit block (1 int4 per thread)
#define MAXB 512             // max bins (N <= 131072)

// ---- K0: zero reservation counters ----
__global__ void zero_kernel(unsigned* __restrict__ p) {
    p[threadIdx.x + blockIdx.x * 256] = 0u;   // 4 x 256 = 1024 words
}

// ---- K1: multisplit, single-read, direct scatter, 782 blocks ----
__global__ __launch_bounds__(512) void multisplit_kernel(
    const int* __restrict__ src, const int* __restrict__ dst, int E, int NB,
    unsigned* __restrict__ gcur_d, unsigned* __restrict__ gcur_s,
    unsigned* __restrict__ bkt_pairs, unsigned char* __restrict__ bkt_srcs)
{
    __shared__ unsigned hist_d[MAXB], cur_d[MAXB], gb_d[MAXB];
    __shared__ unsigned hist_s[MAXB], cur_s[MAXB], gb_s[MAXB];
    int t = threadIdx.x;
    int e0 = blockIdx.x * CHUNK;
    int cnt = min(CHUNK, E - e0);
    hist_d[t] = 0; hist_s[t] = 0; cur_d[t] = 0; cur_s[t] = 0;
    __syncthreads();
    int n4 = cnt >> 2;
    int4 sa = make_int4(-1, -1, -1, -1), da = sa;
    if (t < n4) { sa = ((const int4*)(src + e0))[t]; da = ((const int4*)(dst + e0))[t]; }
    int sc = -1, dc = -1;
    int ti = (n4 << 2) + t;
    if (t < (cnt & 3)) { sc = src[e0 + ti]; dc = dst[e0 + ti]; }
    if (da.x >= 0) {
        atomicAdd(&hist_d[da.x >> SHIFT], 1u); atomicAdd(&hist_s[sa.x >> SHIFT], 1u);
        atomicAdd(&hist_d[da.y >> SHIFT], 1u); atomicAdd(&hist_s[sa.y >> SHIFT], 1u);
        atomicAdd(&hist_d[da.z >> SHIFT], 1u); atomicAdd(&hist_s[sa.z >> SHIFT], 1u);
        atomicAdd(&hist_d[da.w >> SHIFT], 1u); atomicAdd(&hist_s[sa.w >> SHIFT], 1u);
    }
    if (dc >= 0) { atomicAdd(&hist_d[dc >> SHIFT], 1u); atomicAdd(&hist_s[sc >> SHIFT], 1u); }
    __syncthreads();
    if (t < NB) {
        unsigned hd = hist_d[t], hs = hist_s[t];
        if (hd) gb_d[t] = atomicAdd(&gcur_d[t], hd);
        if (hs) gb_s[t] = atomicAdd(&gcur_s[t], hs);
    }
    __syncthreads();
    int dv[5] = {da.x, da.y, da.z, da.w, dc};
    int sv[5] = {sa.x, sa.y, sa.z, sa.w, sc};
#pragma unroll
    for (int j = 0; j < 5; ++j) {
        if (dv[j] < 0) continue;
        int kd = dv[j] >> SHIFT;
        unsigned pos = gb_d[kd] + atomicAdd(&cur_d[kd], 1u);
        if (pos < CAP)
            bkt_pairs[(size_t)kd * CAP + pos] =
                (((unsigned)dv[j] & (BKEYS - 1)) << 17) | (unsigned)sv[j];
        int ks = sv[j] >> SHIFT;
        unsigned pos2 = gb_s[ks] + atomicAdd(&cur_s[ks], 1u);
        if (pos2 < CAP)
            bkt_srcs[(size_t)ks * CAP + pos2] = (unsigned char)(sv[j] & (BKEYS - 1));
    }
}

// ---- K2: half-bin fused out-degree -> norm -> h16 = fp16((X@W)*norm) ----
__global__ __launch_bounds__(512) void degxw_kernel(
    const unsigned char* __restrict__ bkt_srcs, const unsigned* __restrict__ gcur_s,
    const float* __restrict__ X, const float* __restrict__ W,
    int N, unsigned short* __restrict__ h16)
{
    __shared__ float Ws[IN_DIM * HID];   // 8 KB
    __shared__ unsigned cnt[128];
    __shared__ float nrm[128];
    int t = threadIdx.x;
    int blk = blockIdx.x, bin = blk >> 1;
    unsigned half = blk & 1;
    ((float4*)Ws)[t] = ((const float4*)W)[t];     // 512 float4 by 512 threads
    if (t < 128) cnt[t] = 0;
    __syncthreads();
    unsigned m = gcur_s[bin];
    if (m > CAP) m = CAP;
    const unsigned char* bs = bkt_srcs + (size_t)bin * CAP;
    const uchar4* bs4 = (const uchar4*)bs;
    unsigned m4 = m >> 2;
    for (unsigned i = t; i < m4; i += 512) {
        uchar4 kk = bs4[i];
        if ((kk.x >> 7) == half) atomicAdd(&cnt[kk.x & 127], 1u);
        if ((kk.y >> 7) == half) atomicAdd(&cnt[kk.y & 127], 1u);
        if ((kk.z >> 7) == half) atomicAdd(&cnt[kk.z & 127], 1u);
        if ((kk.w >> 7) == half) atomicAdd(&cnt[kk.w & 127], 1u);
    }
    for (unsigned i = (m4 << 2) + t; i < m; i += 512) {
        unsigned k = bs[i];
        if ((k >> 7) == half) atomicAdd(&cnt[k & 127], 1u);
    }
    __syncthreads();
    if (t < 128) nrm[t] = rsqrtf(fmaxf((float)cnt[t], 1.0f));
    __syncthreads();
    int q = t & 7, ln = t >> 3;          // 8 threads/node, 64 nodes/pass
#pragma unroll
    for (int pass = 0; pass < 2; ++pass) {
        int lv = pass * 64 + ln;
        int v = bin * BKEYS + (int)half * 128 + lv;
        if (v < N) {
            const float4* Xr = (const float4*)(X + (size_t)v * IN_DIM);
            float4 acc = make_float4(0.f, 0.f, 0.f, 0.f);
#pragma unroll
            for (int kk = 0; kk < 16; ++kk) {
                float4 xv = Xr[kk];
                int k0 = kk * 4;
                float4 w0 = ((float4*)Ws)[(k0 + 0) * 8 + q];
                float4 w1 = ((float4*)Ws)[(k0 + 1) * 8 + q];
                float4 w2 = ((float4*)Ws)[(k0 + 2) * 8 + q];
                float4 w3 = ((float4*)Ws)[(k0 + 3) * 8 + q];
                acc.x += xv.x * w0.x + xv.y * w1.x + xv.z * w2.x + xv.w * w3.x;
                acc.y += xv.x * w0.y + xv.y * w1.y + xv.z * w2.y + xv.w * w3.y;
                acc.z += xv.x * w0.z + xv.y * w1.z + xv.z * w2.z + xv.w * w3.z;
                acc.w += xv.x * w0.w + xv.y * w1.w + xv.z * w2.w + xv.w * w3.w;
            }
            float s = nrm[lv];
            __half2 a  = __floats2half2_rn(acc.x * s, acc.y * s);
            __half2 b2 = __floats2half2_rn(acc.z * s, acc.w * s);
            uint2 u;
            u.x = *(unsigned*)&a;
            u.y = *(unsigned*)&b2;
            ((uint2*)h16)[(size_t)v * 8 + q] = u;
        }
    }
}

// ---- K3: half-bin LDS CSR build + pull gather + fused epilogue ----
// Gather lane map: lane = node(2b) | slot(2b) | quad(2b): 4 nodes/wave-iter,
// 4 edge-slots, 4 dim-quads; 2-stage shuffle reduction (off 4,8).
__global__ __launch_bounds__(512) void csrgather_kernel(
    const unsigned* __restrict__ bkt_pairs, const unsigned* __restrict__ gcur_d,
    const unsigned short* __restrict__ h16, const float* __restrict__ bias,
    float* __restrict__ out, int N)
{
    __shared__ unsigned cnt[128], ex[128], cur[128];
    __shared__ unsigned ecsr[HCAP];      // 10 KB
    int t = threadIdx.x;
    int blk = blockIdx.x, bin = blk >> 1;
    unsigned half = blk & 1;
    if (t < 128) { cnt[t] = 0; cur[t] = 0; }
    __syncthreads();
    unsigned m = gcur_d[bin];
    if (m > CAP) m = CAP;
    const unsigned* bp = bkt_pairs + (size_t)bin * CAP;
    for (unsigned i = t; i < m; i += 512) {
        unsigned k = bp[i] >> 17;
        if ((k >> 7) == half) atomicAdd(&cnt[k & 127], 1u);
    }
    __syncthreads();
    if (t < 128) ex[t] = cnt[t];
    __syncthreads();
    for (int off = 1; off < 128; off <<= 1) {
        unsigned u = (t >= off && t < 128) ? ex[t - off] : 0;
        __syncthreads();
        if (t < 128) ex[t] += u;         // inclusive
        __syncthreads();
    }
    for (unsigned i = t; i < m; i += 512) {
        unsigned p = bp[i];
        unsigned k = p >> 17;
        if ((k >> 7) == half) {
            unsigned kk = k & 127;
            unsigned pos = (ex[kk] - cnt[kk]) + atomicAdd(&cur[kk], 1u);
            if (pos < HCAP) ecsr[pos] = p & 0x1FFFFu;
        }
    }
    __syncthreads();
    int lane = t & 63, w = t >> 6;
    int n2 = lane >> 4;                  // node within wave-iter 0..3
    int slot = (lane >> 2) & 3;          // edge slot 0..3
    int q = lane & 3;                    // dim quad (16 B of 64 B row)
    float4 bq0 = ((const float4*)bias)[q * 2];
    float4 bq1 = ((const float4*)bias)[q * 2 + 1];
    for (int j = 0; j < 4; ++j) {
        int lv = w * 16 + j * 4 + n2;    // 0..127
        unsigned dg = cnt[lv];
        unsigned st = ex[lv] - dg;
        unsigned en = st + dg; if (en > HCAP) en = HCAP;
        float a0=0.f,a1=0.f,a2=0.f,a3=0.f,a4=0.f,a5=0.f,a6=0.f,a7=0.f;
        unsigned u = st + slot;
        for (; u + 4 < en; u += 8) {     // 2 independent 16B loads in flight
            unsigned s0 = ecsr[u];
            unsigned s1 = ecsr[u + 4];
            uint4 hv0 = ((const uint4*)h16)[(size_t)s0 * 4 + q];
            uint4 hv1 = ((const uint4*)h16)[(size_t)s1 * 4 + q];
            __half2* hp0 = (__half2*)&hv0;
            __half2* hp1 = (__half2*)&hv1;
            float2 f0 = __half22float2(hp0[0]), g0 = __half22float2(hp1[0]);
            float2 f1 = __half22float2(hp0[1]), g1 = __half22float2(hp1[1]);
            float2 f2 = __half22float2(hp0[2]), g2 = __half22float2(hp1[2]);
            float2 f3 = __half22float2(hp0[3]), g3 = __half22float2(hp1[3]);
            a0 += f0.x + g0.x; a1 += f0.y + g0.y;
            a2 += f1.x + g1.x; a3 += f1.y + g1.y;
            a4 += f2.x + g2.x; a5 += f2.y + g2.y;
            a6 += f3.x + g3.x; a7 += f3.y + g3.y;
        }
        if (u < en) {
            unsigned s = ecsr[u];
            uint4 hv = ((const uint4*)h16)[(size_t)s * 4 + q];
            __half2* hp = (__half2*)&hv;
            float2 f0 = __half22float2(hp[0]);
            float2 f1 = __half22float2(hp[1]);
            float2 f2 = __half22float2(hp[2]);
            float2 f3 = __half22float2(hp[3]);
            a0 += f0.x; a1 += f0.y; a2 += f1.x; a3 += f1.y;
            a4 += f2.x; a5 += f2.y; a6 += f3.x; a7 += f3.y;
        }
        // 2-stage reduction over slot bits (lane bits 2,3)
#pragma unroll
        for (int off = 4; off <= 8; off <<= 1) {
            a0 += __shfl_xor(a0, off, 64); a1 += __shfl_xor(a1, off, 64);
            a2 += __shfl_xor(a2, off, 64); a3 += __shfl_xor(a3, off, 64);
            a4 += __shfl_xor(a4, off, 64); a5 += __shfl_xor(a5, off, 64);
            a6 += __shfl_xor(a6, off, 64); a7 += __shfl_xor(a7, off, 64);
        }
        int v = bin * BKEYS + (int)half * 128 + lv;
        if (slot == 0 && v < N) {
            float nv = rsqrtf(fmaxf((float)dg, 1.0f));
            float4 o0, o1;
            o0.x = fmaxf(a0 * nv + bq0.x, 0.f);
            o0.y = fmaxf(a1 * nv + bq0.y, 0.f);
            o0.z = fmaxf(a2 * nv + bq0.z, 0.f);
            o0.w = fmaxf(a3 * nv + bq0.w, 0.f);
            o1.x = fmaxf(a4 * nv + bq1.x, 0.f);
            o1.y = fmaxf(a5 * nv + bq1.y, 0.f);
            o1.z = fmaxf(a6 * nv + bq1.z, 0.f);
            o1.w = fmaxf(a7 * nv + bq1.w, 0.f);
            float* op = out + (size_t)v * HID + q * 8;
            *(float4*)op = o0;
            *(float4*)(op + 4) = o1;
        }
    }
}

extern "C" void kernel_launch(void* const* d_in, const int* in_sizes, int n_in,
                              void* d_out, int out_size, void* d_ws, size_t ws_size,
                              hipStream_t stream) {
    const float* X   = (const float*)d_in[0];
    const int*   src = (const int*)d_in[1];
    const int*   dst = (const int*)d_in[2];
    const float* W   = (const float*)d_in[3];
    const float* b   = (const float*)d_in[4];
    float* out = (float*)d_out;

    int N = in_sizes[0] / IN_DIM;        // 100000
    int E = in_sizes[1];                 // 1600000
    int NB = (N + BKEYS - 1) / BKEYS;    // 391

    // ws: [gcur_d 512 u32][gcur_s 512 u32][bkt_pairs NB*CAP u32]
    //     [bkt_srcs NB*CAP u8][h16 N*32 halves]
    unsigned* gcur_d = (unsigned*)d_ws;
    unsigned* gcur_s = gcur_d + MAXB;
    unsigned* bkt_pairs = gcur_s + MAXB;
    unsigned char* bkt_srcs = (unsigned char*)(bkt_pairs + (size_t)NB * CAP);
    unsigned short* h16 = (unsigned short*)(bkt_srcs + (size_t)NB * CAP);

    zero_kernel<<<4, 256, 0, stream>>>(gcur_d);
    multisplit_kernel<<<(E + CHUNK - 1) / CHUNK, 512, 0, stream>>>(
        src, dst, E, NB, gcur_d, gcur_s, bkt_pairs, bkt_srcs);
    degxw_kernel<<<NB * 2, 512, 0, stream>>>(bkt_srcs, gcur_s, X, W, N, h16);
    csrgather_kernel<<<NB * 2, 512, 0, stream>>>(bkt_pairs, gcur_d, h16, b, out, N);
}

// Round 12
// 151.360 us; speedup vs baseline: 3.5205x; 1.0546x over previous
//
#include <hip/hip_runtime.h>
#include <hip/hip_fp16.h>

#define IN_DIM 64
#define HID 32
#define SHIFT 8
#define BKEYS 256            // nodes per bin
#define CAP 4608             // bin capacity (mean 4096, sigma ~64 -> +8 sigma)
#define HCAP 2560            // half-bin CSR capacity (mean 2048, sigma ~45)
#define CHUNK 4096           // edges per multisplit block (2 int4 per thread)
#define MAXB 512             // max bins (N <= 131072)

// ---- K0: zero reservation counters ----
__global__ void zero_kernel(unsigned* __restrict__ p) {
    p[threadIdx.x + blockIdx.x * 256] = 0u;   // 4 x 256 = 1024 words
}

// ---- K1: multisplit, single-read (edges in registers), direct scatter ----
__global__ __launch_bounds__(512) void multisplit_kernel(
    const int* __restrict__ src, const int* __restrict__ dst, int E, int NB,
    unsigned* __restrict__ gcur_d, unsigned* __restrict__ gcur_s,
    unsigned* __restrict__ bkt_pairs, unsigned char* __restrict__ bkt_srcs)
{
    __shared__ unsigned hist_d[MAXB], cur_d[MAXB], gb_d[MAXB];
    __shared__ unsigned hist_s[MAXB], cur_s[MAXB], gb_s[MAXB];
    int t = threadIdx.x;
    int e0 = blockIdx.x * CHUNK;
    int cnt = min(CHUNK, E - e0);
    hist_d[t] = 0; hist_s[t] = 0; cur_d[t] = 0; cur_s[t] = 0;
    __syncthreads();
    int n4 = cnt >> 2;
    const int4* s4 = (const int4*)(src + e0);
    const int4* d4 = (const int4*)(dst + e0);
    int4 sa = make_int4(-1, -1, -1, -1), da = sa, sb = sa, db = sa;
    if (t < n4)       { sa = s4[t];       da = d4[t]; }
    if (t + 512 < n4) { sb = s4[t + 512]; db = d4[t + 512]; }
    int sc = -1, dc = -1;
    int ti = (n4 << 2) + t;
    if (t < (cnt & 3)) { sc = src[e0 + ti]; dc = dst[e0 + ti]; }
    if (da.x >= 0) { atomicAdd(&hist_d[da.x >> SHIFT], 1u); atomicAdd(&hist_s[sa.x >> SHIFT], 1u);
                     atomicAdd(&hist_d[da.y >> SHIFT], 1u); atomicAdd(&hist_s[sa.y >> SHIFT], 1u);
                     atomicAdd(&hist_d[da.z >> SHIFT], 1u); atomicAdd(&hist_s[sa.z >> SHIFT], 1u);
                     atomicAdd(&hist_d[da.w >> SHIFT], 1u); atomicAdd(&hist_s[sa.w >> SHIFT], 1u); }
    if (db.x >= 0) { atomicAdd(&hist_d[db.x >> SHIFT], 1u); atomicAdd(&hist_s[sb.x >> SHIFT], 1u);
                     atomicAdd(&hist_d[db.y >> SHIFT], 1u); atomicAdd(&hist_s[sb.y >> SHIFT], 1u);
                     atomicAdd(&hist_d[db.z >> SHIFT], 1u); atomicAdd(&hist_s[sb.z >> SHIFT], 1u);
                     atomicAdd(&hist_d[db.w >> SHIFT], 1u); atomicAdd(&hist_s[sb.w >> SHIFT], 1u); }
    if (dc >= 0)   { atomicAdd(&hist_d[dc >> SHIFT], 1u);   atomicAdd(&hist_s[sc >> SHIFT], 1u); }
    __syncthreads();
    if (t < NB) {
        unsigned hd = hist_d[t], hs = hist_s[t];
        if (hd) gb_d[t] = atomicAdd(&gcur_d[t], hd);
        if (hs) gb_s[t] = atomicAdd(&gcur_s[t], hs);
    }
    __syncthreads();
    int dv[9] = {da.x, da.y, da.z, da.w, db.x, db.y, db.z, db.w, dc};
    int sv[9] = {sa.x, sa.y, sa.z, sa.w, sb.x, sb.y, sb.z, sb.w, sc};
#pragma unroll
    for (int j = 0; j < 9; ++j) {
        if (dv[j] < 0) continue;
        int kd = dv[j] >> SHIFT;
        unsigned pos = gb_d[kd] + atomicAdd(&cur_d[kd], 1u);
        if (pos < CAP)
            bkt_pairs[(size_t)kd * CAP + pos] =
                (((unsigned)dv[j] & (BKEYS - 1)) << 17) | (unsigned)sv[j];
        int ks = sv[j] >> SHIFT;
        unsigned pos2 = gb_s[ks] + atomicAdd(&cur_s[ks], 1u);
        if (pos2 < CAP)
            bkt_srcs[(size_t)ks * CAP + pos2] = (unsigned char)(sv[j] & (BKEYS - 1));
    }
}

// ---- K2: half-bin fused out-degree -> norm -> h16 = fp16((X@W)*norm) ----
__global__ __launch_bounds__(512) void degxw_kernel(
    const unsigned char* __restrict__ bkt_srcs, const unsigned* __restrict__ gcur_s,
    const float* __restrict__ X, const float* __restrict__ W,
    int N, unsigned short* __restrict__ h16)
{
    __shared__ float Ws[IN_DIM * HID];   // 8 KB
    __shared__ unsigned cnt[128];
    __shared__ float nrm[128];
    int t = threadIdx.x;
    int blk = blockIdx.x, bin = blk >> 1;
    unsigned half = blk & 1;
    ((float4*)Ws)[t] = ((const float4*)W)[t];     // 512 float4 by 512 threads
    if (t < 128) cnt[t] = 0;
    __syncthreads();
    unsigned m = gcur_s[bin];
    if (m > CAP) m = CAP;
    const unsigned char* bs = bkt_srcs + (size_t)bin * CAP;
    const uchar4* bs4 = (const uchar4*)bs;
    unsigned m4 = m >> 2;
    for (unsigned i = t; i < m4; i += 512) {
        uchar4 kk = bs4[i];
        if ((kk.x >> 7) == half) atomicAdd(&cnt[kk.x & 127], 1u);
        if ((kk.y >> 7) == half) atomicAdd(&cnt[kk.y & 127], 1u);
        if ((kk.z >> 7) == half) atomicAdd(&cnt[kk.z & 127], 1u);
        if ((kk.w >> 7) == half) atomicAdd(&cnt[kk.w & 127], 1u);
    }
    for (unsigned i = (m4 << 2) + t; i < m; i += 512) {
        unsigned k = bs[i];
        if ((k >> 7) == half) atomicAdd(&cnt[k & 127], 1u);
    }
    __syncthreads();
    if (t < 128) nrm[t] = rsqrtf(fmaxf((float)cnt[t], 1.0f));
    __syncthreads();
    int q = t & 7, ln = t >> 3;          // 8 threads/node, 64 nodes/pass
#pragma unroll
    for (int pass = 0; pass < 2; ++pass) {
        int lv = pass * 64 + ln;
        int v = bin * BKEYS + (int)half * 128 + lv;
        if (v < N) {
            const float4* Xr = (const float4*)(X + (size_t)v * IN_DIM);
            float4 acc = make_float4(0.f, 0.f, 0.f, 0.f);
#pragma unroll
            for (int kk = 0; kk < 16; ++kk) {
                float4 xv = Xr[kk];
                int k0 = kk * 4;
                float4 w0 = ((float4*)Ws)[(k0 + 0) * 8 + q];
                float4 w1 = ((float4*)Ws)[(k0 + 1) * 8 + q];
                float4 w2 = ((float4*)Ws)[(k0 + 2) * 8 + q];
                float4 w3 = ((float4*)Ws)[(k0 + 3) * 8 + q];
                acc.x += xv.x * w0.x + xv.y * w1.x + xv.z * w2.x + xv.w * w3.x;
                acc.y += xv.x * w0.y + xv.y * w1.y + xv.z * w2.y + xv.w * w3.y;
                acc.z += xv.x * w0.z + xv.y * w1.z + xv.z * w2.z + xv.w * w3.z;
                acc.w += xv.x * w0.w + xv.y * w1.w + xv.z * w2.w + xv.w * w3.w;
            }
            float s = nrm[lv];
            __half2 a  = __floats2half2_rn(acc.x * s, acc.y * s);
            __half2 b2 = __floats2half2_rn(acc.z * s, acc.w * s);
            uint2 u;
            u.x = *(unsigned*)&a;
            u.y = *(unsigned*)&b2;
            ((uint2*)h16)[(size_t)v * 8 + q] = u;
        }
    }
}

// ---- K3: half-bin LDS CSR build + pull gather + fused epilogue ----
// R8 lane map (8 slots x 2 nodes x 4 quads), j-loop unrolled x2 for MLP.
__global__ __launch_bounds__(512) void csrgather_kernel(
    const unsigned* __restrict__ bkt_pairs, const unsigned* __restrict__ gcur_d,
    const unsigned short* __restrict__ h16, const float* __restrict__ bias,
    float* __restrict__ out, int N)
{
    __shared__ unsigned cnt[128], ex[128], cur[128];
    __shared__ unsigned ecsr[HCAP];      // 10 KB
    int t = threadIdx.x;
    int blk = blockIdx.x, bin = blk >> 1;
    unsigned half = blk & 1;
    if (t < 128) { cnt[t] = 0; cur[t] = 0; }
    __syncthreads();
    unsigned m = gcur_d[bin];
    if (m > CAP) m = CAP;
    const unsigned* bp = bkt_pairs + (size_t)bin * CAP;
    for (unsigned i = t; i < m; i += 512) {
        unsigned k = bp[i] >> 17;
        if ((k >> 7) == half) atomicAdd(&cnt[k & 127], 1u);
    }
    __syncthreads();
    if (t < 128) ex[t] = cnt[t];
    __syncthreads();
    for (int off = 1; off < 128; off <<= 1) {
        unsigned u = (t >= off && t < 128) ? ex[t - off] : 0;
        __syncthreads();
        if (t < 128) ex[t] += u;         // inclusive
        __syncthreads();
    }
    for (unsigned i = t; i < m; i += 512) {
        unsigned p = bp[i];
        unsigned k = p >> 17;
        if ((k >> 7) == half) {
            unsigned kk = k & 127;
            unsigned pos = (ex[kk] - cnt[kk]) + atomicAdd(&cur[kk], 1u);
            if (pos < HCAP) ecsr[pos] = p & 0x1FFFFu;
        }
    }
    __syncthreads();
    int lane = t & 63, w = t >> 6;
    int hsel = lane >> 5, slot = (lane >> 2) & 7, q = lane & 3;
    float4 bq0 = ((const float4*)bias)[q * 2];
    float4 bq1 = ((const float4*)bias)[q * 2 + 1];
#pragma unroll 2
    for (int j = 0; j < 8; ++j) {
        int lv = w * 16 + j * 2 + hsel;  // 0..127
        unsigned dg = cnt[lv];
        unsigned st = ex[lv] - dg;
        unsigned en = st + dg; if (en > HCAP) en = HCAP;
        float a0=0.f,a1=0.f,a2=0.f,a3=0.f,a4=0.f,a5=0.f,a6=0.f,a7=0.f;
        unsigned u = st + slot;
        for (; u + 8 < en; u += 16) {    // two independent 16B loads in flight
            unsigned s0 = ecsr[u];
            unsigned s1 = ecsr[u + 8];
            uint4 hv0 = ((const uint4*)h16)[(size_t)s0 * 4 + q];
            uint4 hv1 = ((const uint4*)h16)[(size_t)s1 * 4 + q];
            __half2* hp0 = (__half2*)&hv0;
            __half2* hp1 = (__half2*)&hv1;
            float2 f0 = __half22float2(hp0[0]), g0 = __half22float2(hp1[0]);
            float2 f1 = __half22float2(hp0[1]), g1 = __half22float2(hp1[1]);
            float2 f2 = __half22float2(hp0[2]), g2 = __half22float2(hp1[2]);
            float2 f3 = __half22float2(hp0[3]), g3 = __half22float2(hp1[3]);
            a0 += f0.x + g0.x; a1 += f0.y + g0.y;
            a2 += f1.x + g1.x; a3 += f1.y + g1.y;
            a4 += f2.x + g2.x; a5 += f2.y + g2.y;
            a6 += f3.x + g3.x; a7 += f3.y + g3.y;
        }
        if (u < en) {
            unsigned s = ecsr[u];
            uint4 hv = ((const uint4*)h16)[(size_t)s * 4 + q];
            __half2* hp = (__half2*)&hv;
            float2 f0 = __half22float2(hp[0]);
            float2 f1 = __half22float2(hp[1]);
            float2 f2 = __half22float2(hp[2]);
            float2 f3 = __half22float2(hp[3]);
            a0 += f0.x; a1 += f0.y; a2 += f1.x; a3 += f1.y;
            a4 += f2.x; a5 += f2.y; a6 += f3.x; a7 += f3.y;
        }
#pragma unroll
        for (int off = 4; off <= 16; off <<= 1) {
            a0 += __shfl_xor(a0, off, 64); a1 += __shfl_xor(a1, off, 64);
            a2 += __shfl_xor(a2, off, 64); a3 += __shfl_xor(a3, off, 64);
            a4 += __shfl_xor(a4, off, 64); a5 += __shfl_xor(a5, off, 64);
            a6 += __shfl_xor(a6, off, 64); a7 += __shfl_xor(a7, off, 64);
        }
        int v = bin * BKEYS + (int)half * 128 + lv;
        if (slot == 0 && v < N) {
            float nv = rsqrtf(fmaxf((float)dg, 1.0f));
            float4 o0, o1;
            o0.x = fmaxf(a0 * nv + bq0.x, 0.f);
            o0.y = fmaxf(a1 * nv + bq0.y, 0.f);
            o0.z = fmaxf(a2 * nv + bq0.z, 0.f);
            o0.w = fmaxf(a3 * nv + bq0.w, 0.f);
            o1.x = fmaxf(a4 * nv + bq1.x, 0.f);
            o1.y = fmaxf(a5 * nv + bq1.y, 0.f);
            o1.z = fmaxf(a6 * nv + bq1.z, 0.f);
            o1.w = fmaxf(a7 * nv + bq1.w, 0.f);
            float* op = out + (size_t)v * HID + q * 8;
            *(float4*)op = o0;
            *(float4*)(op + 4) = o1;
        }
    }
}

extern "C" void kernel_launch(void* const* d_in, const int* in_sizes, int n_in,
                              void* d_out, int out_size, void* d_ws, size_t ws_size,
                              hipStream_t stream) {
    const float* X   = (const float*)d_in[0];
    const int*   src = (const int*)d_in[1];
    const int*   dst = (const int*)d_in[2];
    const float* W   = (const float*)d_in[3];
    const float* b   = (const float*)d_in[4];
    float* out = (float*)d_out;

    int N = in_sizes[0] / IN_DIM;        // 100000
    int E = in_sizes[1];                 // 1600000
    int NB = (N + BKEYS - 1) / BKEYS;    // 391

    // ws: [gcur_d 512 u32][gcur_s 512 u32][bkt_pairs NB*CAP u32]
    //     [bkt_srcs NB*CAP u8][h16 N*32 halves]
    unsigned* gcur_d = (unsigned*)d_ws;
    unsigned* gcur_s = gcur_d + MAXB;
    unsigned* bkt_pairs = gcur_s + MAXB;
    unsigned char* bkt_srcs = (unsigned char*)(bkt_pairs + (size_t)NB * CAP);
    unsigned short* h16 = (unsigned short*)(bkt_srcs + (size_t)NB * CAP);

    zero_kernel<<<4, 256, 0, stream>>>(gcur_d);
    multisplit_kernel<<<(E + CHUNK - 1) / CHUNK, 512, 0, stream>>>(
        src, dst, E, NB, gcur_d, gcur_s, bkt_pairs, bkt_srcs);
    degxw_kernel<<<NB * 2, 512, 0, stream>>>(bkt_srcs, gcur_s, X, W, N, h16);
    csrgather_kernel<<<NB * 2, 512, 0, stream>>>(bkt_pairs, gcur_d, h16, b, out, N);
}

// Round 13
// 145.913 us; speedup vs baseline: 3.6519x; 1.0373x over previous
//
#include <hip/hip_runtime.h>
#include <hip/hip_fp16.h>

#define IN_DIM 64
#define HID 32
#define SHIFT 8
#define BKEYS 256            // nodes per bin
#define CAP 4608             // bin capacity (mean 4096, sigma ~64 -> +8 sigma)
#define HCAP 2560            // half-bin CSR capacity (mean 2048, sigma ~45)
#define CHUNK 4096           // edges per multisplit block (2 int4 per thread)
#define MAXB 512             // max bins (N <= 131072)

// ---- K0: zero reservation counters ----
__global__ void zero_kernel(unsigned* __restrict__ p) {
    p[threadIdx.x + blockIdx.x * 256] = 0u;   // 4 x 256 = 1024 words
}

// ---- K1: multisplit, single-read (edges in registers), direct scatter ----
__global__ __launch_bounds__(512) void multisplit_kernel(
    const int* __restrict__ src, const int* __restrict__ dst, int E, int NB,
    unsigned* __restrict__ gcur_d, unsigned* __restrict__ gcur_s,
    unsigned* __restrict__ bkt_pairs, unsigned char* __restrict__ bkt_srcs)
{
    __shared__ unsigned hist_d[MAXB], cur_d[MAXB], gb_d[MAXB];
    __shared__ unsigned hist_s[MAXB], cur_s[MAXB], gb_s[MAXB];
    int t = threadIdx.x;
    int e0 = blockIdx.x * CHUNK;
    int cnt = min(CHUNK, E - e0);
    hist_d[t] = 0; hist_s[t] = 0; cur_d[t] = 0; cur_s[t] = 0;
    __syncthreads();
    int n4 = cnt >> 2;
    const int4* s4 = (const int4*)(src + e0);
    const int4* d4 = (const int4*)(dst + e0);
    int4 sa = make_int4(-1, -1, -1, -1), da = sa, sb = sa, db = sa;
    if (t < n4)       { sa = s4[t];       da = d4[t]; }
    if (t + 512 < n4) { sb = s4[t + 512]; db = d4[t + 512]; }
    int sc = -1, dc = -1;
    int ti = (n4 << 2) + t;
    if (t < (cnt & 3)) { sc = src[e0 + ti]; dc = dst[e0 + ti]; }
    if (da.x >= 0) { atomicAdd(&hist_d[da.x >> SHIFT], 1u); atomicAdd(&hist_s[sa.x >> SHIFT], 1u);
                     atomicAdd(&hist_d[da.y >> SHIFT], 1u); atomicAdd(&hist_s[sa.y >> SHIFT], 1u);
                     atomicAdd(&hist_d[da.z >> SHIFT], 1u); atomicAdd(&hist_s[sa.z >> SHIFT], 1u);
                     atomicAdd(&hist_d[da.w >> SHIFT], 1u); atomicAdd(&hist_s[sa.w >> SHIFT], 1u); }
    if (db.x >= 0) { atomicAdd(&hist_d[db.x >> SHIFT], 1u); atomicAdd(&hist_s[sb.x >> SHIFT], 1u);
                     atomicAdd(&hist_d[db.y >> SHIFT], 1u); atomicAdd(&hist_s[sb.y >> SHIFT], 1u);
                     atomicAdd(&hist_d[db.z >> SHIFT], 1u); atomicAdd(&hist_s[sb.z >> SHIFT], 1u);
                     atomicAdd(&hist_d[db.w >> SHIFT], 1u); atomicAdd(&hist_s[sb.w >> SHIFT], 1u); }
    if (dc >= 0)   { atomicAdd(&hist_d[dc >> SHIFT], 1u);   atomicAdd(&hist_s[sc >> SHIFT], 1u); }
    __syncthreads();
    if (t < NB) {
        unsigned hd = hist_d[t], hs = hist_s[t];
        if (hd) gb_d[t] = atomicAdd(&gcur_d[t], hd);
        if (hs) gb_s[t] = atomicAdd(&gcur_s[t], hs);
    }
    __syncthreads();
    int dv[9] = {da.x, da.y, da.z, da.w, db.x, db.y, db.z, db.w, dc};
    int sv[9] = {sa.x, sa.y, sa.z, sa.w, sb.x, sb.y, sb.z, sb.w, sc};
#pragma unroll
    for (int j = 0; j < 9; ++j) {
        if (dv[j] < 0) continue;
        int kd = dv[j] >> SHIFT;
        unsigned pos = gb_d[kd] + atomicAdd(&cur_d[kd], 1u);
        if (pos < CAP)
            bkt_pairs[(size_t)kd * CAP + pos] =
                (((unsigned)dv[j] & (BKEYS - 1)) << 17) | (unsigned)sv[j];
        int ks = sv[j] >> SHIFT;
        unsigned pos2 = gb_s[ks] + atomicAdd(&cur_s[ks], 1u);
        if (pos2 < CAP)
            bkt_srcs[(size_t)ks * CAP + pos2] = (unsigned char)(sv[j] & (BKEYS - 1));
    }
}

// ---- K2: half-bin fused out-degree -> norm -> h16 = fp16((X@W)*norm) ----
__global__ __launch_bounds__(512) void degxw_kernel(
    const unsigned char* __restrict__ bkt_srcs, const unsigned* __restrict__ gcur_s,
    const float* __restrict__ X, const float* __restrict__ W,
    int N, unsigned short* __restrict__ h16)
{
    __shared__ float Ws[IN_DIM * HID];   // 8 KB
    __shared__ unsigned cnt[128];
    __shared__ float nrm[128];
    int t = threadIdx.x;
    int blk = blockIdx.x, bin = blk >> 1;
    unsigned half = blk & 1;
    ((float4*)Ws)[t] = ((const float4*)W)[t];     // 512 float4 by 512 threads
    if (t < 128) cnt[t] = 0;
    __syncthreads();
    unsigned m = gcur_s[bin];
    if (m > CAP) m = CAP;
    const unsigned char* bs = bkt_srcs + (size_t)bin * CAP;
    const uchar4* bs4 = (const uchar4*)bs;
    unsigned m4 = m >> 2;
    for (unsigned i = t; i < m4; i += 512) {
        uchar4 kk = bs4[i];
        if ((kk.x >> 7) == half) atomicAdd(&cnt[kk.x & 127], 1u);
        if ((kk.y >> 7) == half) atomicAdd(&cnt[kk.y & 127], 1u);
        if ((kk.z >> 7) == half) atomicAdd(&cnt[kk.z & 127], 1u);
        if ((kk.w >> 7) == half) atomicAdd(&cnt[kk.w & 127], 1u);
    }
    for (unsigned i = (m4 << 2) + t; i < m; i += 512) {
        unsigned k = bs[i];
        if ((k >> 7) == half) atomicAdd(&cnt[k & 127], 1u);
    }
    __syncthreads();
    if (t < 128) nrm[t] = rsqrtf(fmaxf((float)cnt[t], 1.0f));
    __syncthreads();
    int q = t & 7, ln = t >> 3;          // 8 threads/node, 64 nodes/pass
#pragma unroll
    for (int pass = 0; pass < 2; ++pass) {
        int lv = pass * 64 + ln;
        int v = bin * BKEYS + (int)half * 128 + lv;
        if (v < N) {
            const float4* Xr = (const float4*)(X + (size_t)v * IN_DIM);
            float4 acc = make_float4(0.f, 0.f, 0.f, 0.f);
#pragma unroll
            for (int kk = 0; kk < 16; ++kk) {
                float4 xv = Xr[kk];
                int k0 = kk * 4;
                float4 w0 = ((float4*)Ws)[(k0 + 0) * 8 + q];
                float4 w1 = ((float4*)Ws)[(k0 + 1) * 8 + q];
                float4 w2 = ((float4*)Ws)[(k0 + 2) * 8 + q];
                float4 w3 = ((float4*)Ws)[(k0 + 3) * 8 + q];
                acc.x += xv.x * w0.x + xv.y * w1.x + xv.z * w2.x + xv.w * w3.x;
                acc.y += xv.x * w0.y + xv.y * w1.y + xv.z * w2.y + xv.w * w3.y;
                acc.z += xv.x * w0.z + xv.y * w1.z + xv.z * w2.z + xv.w * w3.z;
                acc.w += xv.x * w0.w + xv.y * w1.w + xv.z * w2.w + xv.w * w3.w;
            }
            float s = nrm[lv];
            __half2 a  = __floats2half2_rn(acc.x * s, acc.y * s);
            __half2 b2 = __floats2half2_rn(acc.z * s, acc.w * s);
            uint2 u;
            u.x = *(unsigned*)&a;
            u.y = *(unsigned*)&b2;
            ((uint2*)h16)[(size_t)v * 8 + q] = u;
        }
    }
}

// ---- K3: half-bin LDS CSR build + per-lane gather (no shuffles) ----
// lane = node(4b)|quad(2b): 16 nodes/wave, 4 lanes/node each owning 16 B of the
// h16 row. Each lane streams its node's whole edge list, x4 unrolled -> 4
// independent 16 B loads in flight continuously; no cross-lane reduction.
__global__ __launch_bounds__(512) void csrgather_kernel(
    const unsigned* __restrict__ bkt_pairs, const unsigned* __restrict__ gcur_d,
    const unsigned short* __restrict__ h16, const float* __restrict__ bias,
    float* __restrict__ out, int N)
{
    __shared__ unsigned cnt[128], ex[128], cur[128];
    __shared__ unsigned ecsr[HCAP];      // 10 KB
    int t = threadIdx.x;
    int blk = blockIdx.x, bin = blk >> 1;
    unsigned half = blk & 1;
    if (t < 128) { cnt[t] = 0; cur[t] = 0; }
    __syncthreads();
    unsigned m = gcur_d[bin];
    if (m > CAP) m = CAP;
    const unsigned* bp = bkt_pairs + (size_t)bin * CAP;
    for (unsigned i = t; i < m; i += 512) {
        unsigned k = bp[i] >> 17;
        if ((k >> 7) == half) atomicAdd(&cnt[k & 127], 1u);
    }
    __syncthreads();
    if (t < 128) ex[t] = cnt[t];
    __syncthreads();
    for (int off = 1; off < 128; off <<= 1) {
        unsigned u = (t >= off && t < 128) ? ex[t - off] : 0;
        __syncthreads();
        if (t < 128) ex[t] += u;         // inclusive
        __syncthreads();
    }
    for (unsigned i = t; i < m; i += 512) {
        unsigned p = bp[i];
        unsigned k = p >> 17;
        if ((k >> 7) == half) {
            unsigned kk = k & 127;
            unsigned pos = (ex[kk] - cnt[kk]) + atomicAdd(&cur[kk], 1u);
            if (pos < HCAP) ecsr[pos] = p & 0x1FFFFu;
        }
    }
    __syncthreads();
    int lane = t & 63, w = t >> 6;
    int n16 = lane >> 2;                 // node 0..15 within wave
    int q = lane & 3;                    // dim quad (16 B of 64 B fp16 row)
    int lv = w * 16 + n16;               // 0..127
    unsigned dg = cnt[lv];
    unsigned en = ex[lv]; if (en > HCAP) en = HCAP;
    unsigned st = ex[lv] - dg; if (st > en) st = en;
    unsigned len = en - st;
    const uint4* h16q = (const uint4*)h16;

    float a0=0.f,a1=0.f,a2=0.f,a3=0.f,a4=0.f,a5=0.f,a6=0.f,a7=0.f;
    unsigned i = 0;
    for (; i + 4 <= len; i += 4) {       // 4 independent 16B loads in flight
        unsigned s0 = ecsr[st + i];
        unsigned s1 = ecsr[st + i + 1];
        unsigned s2 = ecsr[st + i + 2];
        unsigned s3 = ecsr[st + i + 3];
        uint4 h0 = h16q[(size_t)s0 * 4 + q];
        uint4 h1 = h16q[(size_t)s1 * 4 + q];
        uint4 h2 = h16q[(size_t)s2 * 4 + q];
        uint4 h3 = h16q[(size_t)s3 * 4 + q];
        __half2* p0 = (__half2*)&h0;  __half2* p1 = (__half2*)&h1;
        __half2* p2 = (__half2*)&h2;  __half2* p3 = (__half2*)&h3;
        float2 f;
        f = __half22float2(p0[0]); a0 += f.x; a1 += f.y;
        f = __half22float2(p0[1]); a2 += f.x; a3 += f.y;
        f = __half22float2(p0[2]); a4 += f.x; a5 += f.y;
        f = __half22float2(p0[3]); a6 += f.x; a7 += f.y;
        f = __half22float2(p1[0]); a0 += f.x; a1 += f.y;
        f = __half22float2(p1[1]); a2 += f.x; a3 += f.y;
        f = __half22float2(p1[2]); a4 += f.x; a5 += f.y;
        f = __half22float2(p1[3]); a6 += f.x; a7 += f.y;
        f = __half22float2(p2[0]); a0 += f.x; a1 += f.y;
        f = __half22float2(p2[1]); a2 += f.x; a3 += f.y;
        f = __half22float2(p2[2]); a4 += f.x; a5 += f.y;
        f = __half22float2(p2[3]); a6 += f.x; a7 += f.y;
        f = __half22float2(p3[0]); a0 += f.x; a1 += f.y;
        f = __half22float2(p3[1]); a2 += f.x; a3 += f.y;
        f = __half22float2(p3[2]); a4 += f.x; a5 += f.y;
        f = __half22float2(p3[3]); a6 += f.x; a7 += f.y;
    }
    for (; i < len; ++i) {
        unsigned s = ecsr[st + i];
        uint4 hv = h16q[(size_t)s * 4 + q];
        __half2* hp = (__half2*)&hv;
        float2 f;
        f = __half22float2(hp[0]); a0 += f.x; a1 += f.y;
        f = __half22float2(hp[1]); a2 += f.x; a3 += f.y;
        f = __half22float2(hp[2]); a4 += f.x; a5 += f.y;
        f = __half22float2(hp[3]); a6 += f.x; a7 += f.y;
    }
    int v = bin * BKEYS + (int)half * 128 + lv;
    if (v < N) {
        float nv = rsqrtf(fmaxf((float)dg, 1.0f));
        float4 bq0 = ((const float4*)bias)[q * 2];
        float4 bq1 = ((const float4*)bias)[q * 2 + 1];
        float4 o0, o1;
        o0.x = fmaxf(a0 * nv + bq0.x, 0.f);
        o0.y = fmaxf(a1 * nv + bq0.y, 0.f);
        o0.z = fmaxf(a2 * nv + bq0.z, 0.f);
        o0.w = fmaxf(a3 * nv + bq0.w, 0.f);
        o1.x = fmaxf(a4 * nv + bq1.x, 0.f);
        o1.y = fmaxf(a5 * nv + bq1.y, 0.f);
        o1.z = fmaxf(a6 * nv + bq1.z, 0.f);
        o1.w = fmaxf(a7 * nv + bq1.w, 0.f);
        float* op = out + (size_t)v * HID + q * 8;
        *(float4*)op = o0;
        *(float4*)(op + 4) = o1;
    }
}

extern "C" void kernel_launch(void* const* d_in, const int* in_sizes, int n_in,
                              void* d_out, int out_size, void* d_ws, size_t ws_size,
                              hipStream_t stream) {
    const float* X   = (const float*)d_in[0];
    const int*   src = (const int*)d_in[1];
    const int*   dst = (const int*)d_in[2];
    const float* W   = (const float*)d_in[3];
    const float* b   = (const float*)d_in[4];
    float* out = (float*)d_out;

    int N = in_sizes[0] / IN_DIM;        // 100000
    int E = in_sizes[1];                 // 1600000
    int NB = (N + BKEYS - 1) / BKEYS;    // 391

    // ws: [gcur_d 512 u32][gcur_s 512 u32][bkt_pairs NB*CAP u32]
    //     [bkt_srcs NB*CAP u8][h16 N*32 halves]
    unsigned* gcur_d = (unsigned*)d_ws;
    unsigned* gcur_s = gcur_d + MAXB;
    unsigned* bkt_pairs = gcur_s + MAXB;
    unsigned char* bkt_srcs = (unsigned char*)(bkt_pairs + (size_t)NB * CAP);
    unsigned short* h16 = (unsigned short*)(bkt_srcs + (size_t)NB * CAP);

    zero_kernel<<<4, 256, 0, stream>>>(gcur_d);
    multisplit_kernel<<<(E + CHUNK - 1) / CHUNK, 512, 0, stream>>>(
        src, dst, E, NB, gcur_d, gcur_s, bkt_pairs, bkt_srcs);
    degxw_kernel<<<NB * 2, 512, 0, stream>>>(bkt_srcs, gcur_s, X, W, N, h16);
    csrgather_kernel<<<NB * 2, 512, 0, stream>>>(bkt_pairs, gcur_d, h16, b, out, N);
}